// Round 3
// baseline (268.469 us; speedup 1.0000x reference)
//
#include <hip/hip_runtime.h>

#define Bn 4
#define Nn 4096000
#define Kn 409664
#define R0c 3686399u
#define R1c 3686400u

// ws offsets (u32 units)
#define H1_OFF 0          // B*2048
#define H2_OFF 8192       // B*2048 used (B*2*2048 reserved)
#define H3_OFF 24576      // B*2*1024
#define ST_OFF 32768      // B*4  {key/prefix0, rem0, key/prefix1, rem1}
#define CNT_OFF 32784     // B
#define BC_OFF 32788      // B*1000
#define FLAG_OFF 36788    // B   (1 if both ranks in same top-11 bucket)
#define TOP_OFF 36792     // B   (top-11 prefix)
#define MAX_OFF 36796     // B   (init 0)
#define CC_OFF 36800      // B   (collect counters, init 0)
#define MIN_OFF 36804     // B   (init 0xFFFFFFFF)

#define SCRATCH_CAP 1600000   // floats per sample, scratch lives in `out`
#define SCAP 1024             // max buffered rows per scatter block

#define OUT_SP  ((size_t)Bn * Kn * 5)
#define OUT_VAL ((size_t)Bn * Kn * 9)

__device__ __forceinline__ unsigned fkey(float x) {
    unsigned u = __float_as_uint(x);
    return u ^ ((unsigned)((int)u >> 31) | 0x80000000u);
}
__device__ __forceinline__ float keyf(unsigned k) {
    unsigned u = (k & 0x80000000u) ? (k & 0x7FFFFFFFu) : ~k;
    return __uint_as_float(u);
}

// boundary float: smallest float bv such that (double)bv > thr.
// Then ((double)x > thr)  <=>  (x >= bv)  for float x (no NaN in data).
__device__ __forceinline__ float boundary_from_ws(const unsigned* __restrict__ ws, int b) {
    float vlo = keyf(ws[ST_OFF + b * 4 + 0]);
    float vhi = keyf(ws[ST_OFF + b * 4 + 2]);
    double thr = (double)vlo + 0.1 * ((double)vhi - (double)vlo);
    float c = (float)thr;
    if ((double)c > thr) return c;
    return keyf(fkey(c) + 1u);
}

// ---------------- histogram pass 1: top 11 bits (per-wave privatized) ----------------
__global__ void hist1_k(const float* __restrict__ cube, unsigned* __restrict__ ws) {
    __shared__ unsigned h[4][2048];
    int tid = threadIdx.x, blk = blockIdx.x;
    int b = blk / 250, c = blk % 250;
    int wid = tid >> 6;
    unsigned* hw = h[wid];
    unsigned* hl = &h[0][0];
    for (int j = tid; j < 8192; j += 256) hl[j] = 0;
    __syncthreads();
    const float4* p = (const float4*)(cube + (size_t)b * Nn + (size_t)c * 16384);
    for (int it = 0; it < 16; ++it) {
        float4 v = p[it * 256 + tid];
        atomicAdd(&hw[fkey(v.x) >> 21], 1u);
        atomicAdd(&hw[fkey(v.y) >> 21], 1u);
        atomicAdd(&hw[fkey(v.z) >> 21], 1u);
        atomicAdd(&hw[fkey(v.w) >> 21], 1u);
    }
    __syncthreads();
    unsigned* g = ws + H1_OFF + b * 2048;
    for (int j = tid; j < 2048; j += 256) {
        unsigned s = h[0][j] + h[1][j] + h[2][j] + h[3][j];
        if (s) atomicAdd(&g[j], s);
    }
}

// ---------------- pick from pass-1 histogram (both ranks) + flag/top ----------------
__global__ void pick1_k(unsigned* __restrict__ ws) {
    __shared__ unsigned sh[256];
    int tid = threadIdx.x, b = blockIdx.x;
    const unsigned* hist = ws + H1_OFF + b * 2048;
    unsigned loc[8], lsum = 0;
    for (int j = 0; j < 8; ++j) { loc[j] = hist[tid * 8 + j]; lsum += loc[j]; }
    sh[tid] = lsum; __syncthreads();
    for (int off = 1; off < 256; off <<= 1) {
        unsigned v = (tid >= off) ? sh[tid - off] : 0u; __syncthreads();
        sh[tid] += v; __syncthreads();
    }
    unsigned base = tid ? sh[tid - 1] : 0u;
    unsigned ranks[2] = {R0c, R1c};
    for (int pth = 0; pth < 2; ++pth) {
        unsigned r = ranks[pth];
        if (r >= base && r < base + lsum) {
            unsigned cacc = base;
            for (int j = 0; j < 8; ++j) {
                if (r < cacc + loc[j]) {
                    ws[ST_OFF + b * 4 + pth * 2] = (unsigned)(tid * 8 + j);
                    ws[ST_OFF + b * 4 + pth * 2 + 1] = r - cacc;
                    break;
                }
                cacc += loc[j];
            }
        }
    }
    __syncthreads();
    if (tid == 0) {
        unsigned q0 = ws[ST_OFF + b * 4 + 0];
        unsigned q1 = ws[ST_OFF + b * 4 + 2];
        ws[FLAG_OFF + b] = (q0 == q1) ? 1u : 0u;
        ws[TOP_OFF + b] = q0;
    }
}

// ---------------- collect: append candidate-bucket values to scratch (in out) ----------------
__global__ void collect_k(const float* __restrict__ cube, float* __restrict__ out,
                          unsigned* __restrict__ ws) {
    __shared__ unsigned sh[256];
    __shared__ unsigned base_sh;
    int tid = threadIdx.x, blk = blockIdx.x;
    int b = blk / 250, c = blk % 250;
    unsigned p0 = ws[ST_OFF + b * 4 + 0];
    unsigned p1 = ws[ST_OFF + b * 4 + 2];
    const float4* p = (const float4*)(cube + (size_t)b * Nn + (size_t)c * 16384);
    if (p0 == p1) {
        unsigned cnt = 0;
        for (int it = 0; it < 16; ++it) {
            float4 v = p[it * 256 + tid];
            cnt += (unsigned)((fkey(v.x) >> 21) == p0) + (unsigned)((fkey(v.y) >> 21) == p0)
                 + (unsigned)((fkey(v.z) >> 21) == p0) + (unsigned)((fkey(v.w) >> 21) == p0);
        }
        sh[tid] = cnt; __syncthreads();
        for (int off = 1; off < 256; off <<= 1) {
            unsigned v = (tid >= off) ? sh[tid - off] : 0u; __syncthreads();
            sh[tid] += v; __syncthreads();
        }
        if (tid == 255) base_sh = atomicAdd(&ws[CC_OFF + b], sh[255]);
        __syncthreads();
        unsigned idx = base_sh + sh[tid] - cnt;
        float* dst = out + (size_t)b * SCRATCH_CAP;
        for (int it = 0; it < 16; ++it) {
            float4 v = p[it * 256 + tid];
            float vv[4] = {v.x, v.y, v.z, v.w};
            for (int q = 0; q < 4; ++q) {
                if ((fkey(vv[q]) >> 21) == p0) {
                    if (idx < SCRATCH_CAP) dst[idx] = vv[q];
                    ++idx;
                }
            }
        }
    } else {
        // ranks straddle buckets: vlo = max of bucket p0, vhi = min of bucket p1
        unsigned mx = 0u, mn = 0xFFFFFFFFu;
        for (int it = 0; it < 16; ++it) {
            float4 v = p[it * 256 + tid];
            float vv[4] = {v.x, v.y, v.z, v.w};
            for (int q = 0; q < 4; ++q) {
                unsigned k = fkey(vv[q]);
                unsigned top = k >> 21;
                if (top == p0) mx = max(mx, k);
                if (top == p1) mn = min(mn, k);
            }
        }
        sh[tid] = mx; __syncthreads();
        for (int off = 128; off > 0; off >>= 1) {
            if (tid < off) sh[tid] = max(sh[tid], sh[tid + off]);
            __syncthreads();
        }
        unsigned bmx = sh[0]; __syncthreads();
        sh[tid] = mn; __syncthreads();
        for (int off = 128; off > 0; off >>= 1) {
            if (tid < off) sh[tid] = min(sh[tid], sh[tid + off]);
            __syncthreads();
        }
        if (tid == 0) {
            if (bmx) atomicMax(&ws[MAX_OFF + b], bmx);
            if (sh[0] != 0xFFFFFFFFu) atomicMin(&ws[MIN_OFF + b], sh[0]);
        }
    }
}

// ---------------- refine A: bits [20:10] over collected values ----------------
__global__ void hist2b_k(const float* __restrict__ scratch, unsigned* __restrict__ ws) {
    __shared__ unsigned h[2048];
    int tid = threadIdx.x, blk = blockIdx.x;
    int b = blk >> 6, g = blk & 63;
    if (!ws[FLAG_OFF + b]) return;
    unsigned M = min(ws[CC_OFF + b], (unsigned)SCRATCH_CAP);
    for (int j = tid; j < 2048; j += 256) h[j] = 0;
    __syncthreads();
    const float* src = scratch + (size_t)b * SCRATCH_CAP;
    for (unsigned i = (unsigned)g * 256u + tid; i < M; i += 64u * 256u)
        atomicAdd(&h[(fkey(src[i]) >> 10) & 0x7FFu], 1u);
    __syncthreads();
    unsigned* gd = ws + H2_OFF + b * 2048;
    for (int j = tid; j < 2048; j += 256) if (h[j]) atomicAdd(&gd[j], h[j]);
}

__global__ void pick2b_k(unsigned* __restrict__ ws) {
    __shared__ unsigned sh[256];
    int tid = threadIdx.x, b = blockIdx.x;
    if (!ws[FLAG_OFF + b]) return;
    const unsigned* hist = ws + H2_OFF + b * 2048;
    unsigned rem0 = ws[ST_OFF + b * 4 + 1];
    unsigned rem1 = ws[ST_OFF + b * 4 + 3];
    unsigned loc[8], lsum = 0;
    for (int j = 0; j < 8; ++j) { loc[j] = hist[tid * 8 + j]; lsum += loc[j]; }
    sh[tid] = lsum; __syncthreads();
    for (int off = 1; off < 256; off <<= 1) {
        unsigned v = (tid >= off) ? sh[tid - off] : 0u; __syncthreads();
        sh[tid] += v; __syncthreads();
    }
    unsigned base = tid ? sh[tid - 1] : 0u;
    unsigned ranks[2] = {rem0, rem1};
    for (int pth = 0; pth < 2; ++pth) {
        unsigned r = ranks[pth];
        if (r >= base && r < base + lsum) {
            unsigned cacc = base;
            for (int j = 0; j < 8; ++j) {
                if (r < cacc + loc[j]) {
                    ws[ST_OFF + b * 4 + pth * 2] = (unsigned)(tid * 8 + j);
                    ws[ST_OFF + b * 4 + pth * 2 + 1] = r - cacc;
                    break;
                }
                cacc += loc[j];
            }
        }
    }
}

// ---------------- refine B: low 10 bits over collected values ----------------
__global__ void hist3b_k(const float* __restrict__ scratch, unsigned* __restrict__ ws) {
    __shared__ unsigned h0[1024], h1[1024];
    int tid = threadIdx.x, blk = blockIdx.x;
    int b = blk >> 6, g = blk & 63;
    if (!ws[FLAG_OFF + b]) return;
    unsigned mid0 = ws[ST_OFF + b * 4 + 0];
    unsigned mid1 = ws[ST_OFF + b * 4 + 2];
    unsigned M = min(ws[CC_OFF + b], (unsigned)SCRATCH_CAP);
    for (int j = tid; j < 1024; j += 256) { h0[j] = 0; h1[j] = 0; }
    __syncthreads();
    const float* src = scratch + (size_t)b * SCRATCH_CAP;
    for (unsigned i = (unsigned)g * 256u + tid; i < M; i += 64u * 256u) {
        unsigned k = fkey(src[i]);
        unsigned mid = (k >> 10) & 0x7FFu;
        unsigned low = k & 0x3FFu;
        if (mid == mid0) atomicAdd(&h0[low], 1u);
        if (mid == mid1) atomicAdd(&h1[low], 1u);
    }
    __syncthreads();
    unsigned* g0 = ws + H3_OFF + (b * 2) * 1024;
    unsigned* g1 = g0 + 1024;
    for (int j = tid; j < 1024; j += 256) {
        if (h0[j]) atomicAdd(&g0[j], h0[j]);
        if (h1[j]) atomicAdd(&g1[j], h1[j]);
    }
}

__global__ void pick3b_k(unsigned* __restrict__ ws) {
    __shared__ unsigned sh[256];
    int tid = threadIdx.x; int b = blockIdx.x >> 1, pth = blockIdx.x & 1;
    if (!ws[FLAG_OFF + b]) {
        if (tid == 0) {
            if (pth == 0) ws[ST_OFF + b * 4 + 0] = ws[MAX_OFF + b];
            else          ws[ST_OFF + b * 4 + 2] = ws[MIN_OFF + b];
        }
        return;
    }
    const unsigned* hist = ws + H3_OFF + (b * 2 + pth) * 1024;
    unsigned r = ws[ST_OFF + b * 4 + pth * 2 + 1];
    unsigned mid = ws[ST_OFF + b * 4 + pth * 2];
    unsigned top = ws[TOP_OFF + b];
    unsigned loc[4], lsum = 0;
    for (int j = 0; j < 4; ++j) { loc[j] = hist[tid * 4 + j]; lsum += loc[j]; }
    sh[tid] = lsum; __syncthreads();
    for (int off = 1; off < 256; off <<= 1) {
        unsigned v = (tid >= off) ? sh[tid - off] : 0u; __syncthreads();
        sh[tid] += v; __syncthreads();
    }
    unsigned base = tid ? sh[tid - 1] : 0u;
    if (r >= base && r < base + lsum) {
        unsigned cacc = base;
        for (int j = 0; j < 4; ++j) {
            if (r < cacc + loc[j]) {
                ws[ST_OFF + b * 4 + pth * 2] = (top << 21) | (mid << 10) | (unsigned)(tid * 4 + j);
                break;
            }
            cacc += loc[j];
        }
    }
}

// ---------------- per-block mask counts ----------------
__global__ void count_k(const float* __restrict__ cube, unsigned* __restrict__ ws) {
    __shared__ unsigned wcnt_sh[4];
    int tid = threadIdx.x, blk = blockIdx.x;
    int b = blk / 1000, c = blk % 1000;
    int lane = tid & 63, wid = tid >> 6;
    float bval = boundary_from_ws(ws, b);
    const float4* p = (const float4*)(cube + (size_t)b * Nn + (size_t)c * 4096 + (size_t)wid * 1024);
    float4 cv[4];
#pragma unroll
    for (int t = 0; t < 4; ++t) cv[t] = p[t * 64 + lane];
    unsigned wcnt = 0;
#pragma unroll
    for (int t = 0; t < 4; ++t) {
        wcnt += (unsigned)__popcll(__ballot(cv[t].x >= bval));
        wcnt += (unsigned)__popcll(__ballot(cv[t].y >= bval));
        wcnt += (unsigned)__popcll(__ballot(cv[t].z >= bval));
        wcnt += (unsigned)__popcll(__ballot(cv[t].w >= bval));
    }
    if (lane == 0) wcnt_sh[wid] = wcnt;
    __syncthreads();
    if (tid == 0) ws[BC_OFF + b * 1000 + c] = wcnt_sh[0] + wcnt_sh[1] + wcnt_sh[2] + wcnt_sh[3];
}

// ---------------- exclusive scan of 1000 block counts per sample ----------------
__global__ void scan_k(unsigned* __restrict__ ws) {
    __shared__ unsigned sh[256];
    int tid = threadIdx.x, b = blockIdx.x;
    unsigned* bc = ws + BC_OFF + b * 1000;
    unsigned loc[4], lsum = 0;
    for (int j = 0; j < 4; ++j) {
        int idx = tid * 4 + j;
        loc[j] = (idx < 1000) ? bc[idx] : 0u;
        lsum += loc[j];
    }
    sh[tid] = lsum; __syncthreads();
    for (int off = 1; off < 256; off <<= 1) {
        unsigned v = (tid >= off) ? sh[tid - off] : 0u; __syncthreads();
        sh[tid] += v; __syncthreads();
    }
    unsigned run = tid ? sh[tid - 1] : 0u;
    for (int j = 0; j < 4; ++j) {
        int idx = tid * 4 + j;
        if (idx < 1000) bc[idx] = run;
        run += loc[j];
    }
    if (tid == 255) ws[CNT_OFF + b] = sh[255];
}

// ---------------- ordered scatter: LDS row buffer + coalesced region writes ----------------
__device__ __forceinline__ void stash_row(float* __restrict__ fbuf, unsigned* __restrict__ pbuf,
                                          unsigned r, int i, float x, float d) {
    int xi = i % 320;
    int t = i / 320;
    int yi = t % 320;
    int zi = t / 320;
    fbuf[r * 5 + 0] = (float)xi / 320.0f * 72.0f;
    fbuf[r * 5 + 1] = (float)yi / 320.0f * 32.0f;
    fbuf[r * 5 + 2] = (float)zi / 40.0f * 8.0f;
    fbuf[r * 5 + 3] = x / 1e13f;
    fbuf[r * 5 + 4] = d - 1.9326f;
    pbuf[r] = ((unsigned)zi << 18) | ((unsigned)yi << 9) | (unsigned)xi;
}

__device__ __forceinline__ void emit_row(float* __restrict__ out, int b, unsigned k,
                                         int i, float x, float d) {
    size_t row = (size_t)b * Kn + k;
    int xi = i % 320;
    int t = i / 320;
    int yi = t % 320;
    int zi = t / 320;
    float* f = out + row * 5;
    f[0] = (float)xi / 320.0f * 72.0f;
    f[1] = (float)yi / 320.0f * 32.0f;
    f[2] = (float)zi / 40.0f * 8.0f;
    f[3] = x / 1e13f;
    f[4] = d - 1.9326f;
    float* s = out + OUT_SP + row * 4;
    s[0] = (float)b; s[1] = (float)zi; s[2] = (float)yi; s[3] = (float)xi;
    out[OUT_VAL + row] = 1.0f;
}

__global__ void scatter_k(const float* __restrict__ cube, const float* __restrict__ dop,
                          float* __restrict__ out, const unsigned* __restrict__ ws) {
    __shared__ float fbuf[SCAP * 5];
    __shared__ unsigned pbuf[SCAP];
    __shared__ unsigned wcnt_sh[4];
    int tid = threadIdx.x, blk = blockIdx.x;
    int b = blk / 1000, c = blk % 1000;
    int lane = tid & 63, wid = tid >> 6;
    float bval = boundary_from_ws(ws, b);

    size_t chunk = (size_t)b * Nn + (size_t)c * 4096 + (size_t)wid * 1024;
    const float4* pc = (const float4*)(cube + chunk);
    const float4* pd = (const float4*)(dop + chunk);

    float4 cv[4], dv4[4];
#pragma unroll
    for (int t = 0; t < 4; ++t) { cv[t] = pc[t * 64 + lane]; dv4[t] = pd[t * 64 + lane]; }
    unsigned wcnt = 0;
#pragma unroll
    for (int t = 0; t < 4; ++t) {
        wcnt += (unsigned)__popcll(__ballot(cv[t].x >= bval));
        wcnt += (unsigned)__popcll(__ballot(cv[t].y >= bval));
        wcnt += (unsigned)__popcll(__ballot(cv[t].z >= bval));
        wcnt += (unsigned)__popcll(__ballot(cv[t].w >= bval));
    }
    if (lane == 0) wcnt_sh[wid] = wcnt;
    __syncthreads();

    unsigned k0 = ws[BC_OFF + b * 1000 + c];
    unsigned total = wcnt_sh[0] + wcnt_sh[1] + wcnt_sh[2] + wcnt_sh[3];
    unsigned wbase = 0;
    for (int w = 0; w < wid; ++w) wbase += wcnt_sh[w];

    unsigned long long lt = (1ull << lane) - 1ull;
    int i0base = c * 4096 + wid * 1024 + lane * 4;

    if (total <= SCAP) {
        unsigned wb = wbase;
#pragma unroll
        for (int t = 0; t < 4; ++t) {
            bool m0 = cv[t].x >= bval, m1 = cv[t].y >= bval, m2 = cv[t].z >= bval, m3 = cv[t].w >= bval;
            unsigned long long b0 = __ballot(m0), b1 = __ballot(m1), b2 = __ballot(m2), b3 = __ballot(m3);
            unsigned s_all = (unsigned)__popcll(b0 & lt) + (unsigned)__popcll(b1 & lt)
                           + (unsigned)__popcll(b2 & lt) + (unsigned)__popcll(b3 & lt);
            unsigned r = wb + s_all;
            int i0 = i0base + t * 256;
            if (m0) stash_row(fbuf, pbuf, r, i0 + 0, cv[t].x, dv4[t].x);
            r += (unsigned)m0;
            if (m1) stash_row(fbuf, pbuf, r, i0 + 1, cv[t].y, dv4[t].y);
            r += (unsigned)m1;
            if (m2) stash_row(fbuf, pbuf, r, i0 + 2, cv[t].z, dv4[t].z);
            r += (unsigned)m2;
            if (m3) stash_row(fbuf, pbuf, r, i0 + 3, cv[t].w, dv4[t].w);
            wb += (unsigned)__popcll(b0) + (unsigned)__popcll(b1)
                + (unsigned)__popcll(b2) + (unsigned)__popcll(b3);
        }
        __syncthreads();
        size_t row0 = (size_t)b * Kn + k0;
        float* f0 = out + row0 * 5;
        for (int j = tid; j < (int)(total * 5); j += 256) f0[j] = fbuf[j];
        float* s0 = out + OUT_SP + row0 * 4;
        for (int j = tid; j < (int)(total * 4); j += 256) {
            unsigned pk = pbuf[j >> 2];
            int comp = j & 3;
            float val;
            if (comp == 0) val = (float)b;
            else if (comp == 1) val = (float)(pk >> 18);
            else if (comp == 2) val = (float)((pk >> 9) & 511u);
            else val = (float)(pk & 511u);
            s0[j] = val;
        }
        float* v0 = out + OUT_VAL + row0;
        for (int j = tid; j < (int)total; j += 256) v0[j] = 1.0f;
    } else {
        // fallback: direct scattered emit (never taken on bench data)
        unsigned wb = k0 + wbase;
#pragma unroll
        for (int t = 0; t < 4; ++t) {
            bool m0 = cv[t].x >= bval, m1 = cv[t].y >= bval, m2 = cv[t].z >= bval, m3 = cv[t].w >= bval;
            unsigned long long b0 = __ballot(m0), b1 = __ballot(m1), b2 = __ballot(m2), b3 = __ballot(m3);
            unsigned s_all = (unsigned)__popcll(b0 & lt) + (unsigned)__popcll(b1 & lt)
                           + (unsigned)__popcll(b2 & lt) + (unsigned)__popcll(b3 & lt);
            unsigned r = wb + s_all;
            int i0 = i0base + t * 256;
            if (m0) emit_row(out, b, r, i0 + 0, cv[t].x, dv4[t].x);
            r += (unsigned)m0;
            if (m1) emit_row(out, b, r, i0 + 1, cv[t].y, dv4[t].y);
            r += (unsigned)m1;
            if (m2) emit_row(out, b, r, i0 + 2, cv[t].z, dv4[t].z);
            r += (unsigned)m2;
            if (m3) emit_row(out, b, r, i0 + 3, cv[t].w, dv4[t].w);
            wb += (unsigned)__popcll(b0) + (unsigned)__popcll(b1)
                + (unsigned)__popcll(b2) + (unsigned)__popcll(b3);
        }
    }
}

// ---------------- zero-fill invalid tail rows ----------------
__global__ void fill_k(float* __restrict__ out, const unsigned* __restrict__ ws) {
    int g = blockIdx.x * 256 + threadIdx.x;
    if (g >= Bn * Kn) return;
    int b = g / Kn;
    int k = g - b * Kn;
    if ((unsigned)k >= ws[CNT_OFF + b]) {
        size_t row = (size_t)g;
        float* f = out + row * 5;
        f[0] = 0.f; f[1] = 0.f; f[2] = 0.f; f[3] = 0.f; f[4] = 0.f;
        float* s = out + OUT_SP + row * 4;
        s[0] = 0.f; s[1] = 0.f; s[2] = 0.f; s[3] = 0.f;
        out[OUT_VAL + row] = 0.f;
    }
}

extern "C" void kernel_launch(void* const* d_in, const int* in_sizes, int n_in,
                              void* d_out, int out_size, void* d_ws, size_t ws_size,
                              hipStream_t stream) {
    const float* cube = (const float*)d_in[0];
    const float* dop = (const float*)d_in[1];
    float* out = (float*)d_out;
    unsigned* ws = (unsigned*)d_ws;

    hipMemsetAsync(d_ws, 0, 32768 * sizeof(unsigned), stream);                     // hists
    hipMemsetAsync((char*)d_ws + (size_t)MAX_OFF * 4, 0, 2 * Bn * sizeof(unsigned), stream);   // MAX, CC
    hipMemsetAsync((char*)d_ws + (size_t)MIN_OFF * 4, 0xFF, Bn * sizeof(unsigned), stream);    // MIN

    hipLaunchKernelGGL(hist1_k, dim3(Bn * 250), dim3(256), 0, stream, cube, ws);
    hipLaunchKernelGGL(pick1_k, dim3(Bn), dim3(256), 0, stream, ws);
    hipLaunchKernelGGL(collect_k, dim3(Bn * 250), dim3(256), 0, stream, cube, out, ws);
    hipLaunchKernelGGL(hist2b_k, dim3(Bn * 64), dim3(256), 0, stream, (const float*)out, ws);
    hipLaunchKernelGGL(pick2b_k, dim3(Bn), dim3(256), 0, stream, ws);
    hipLaunchKernelGGL(hist3b_k, dim3(Bn * 64), dim3(256), 0, stream, (const float*)out, ws);
    hipLaunchKernelGGL(pick3b_k, dim3(Bn * 2), dim3(256), 0, stream, ws);
    hipLaunchKernelGGL(count_k, dim3(Bn * 1000), dim3(256), 0, stream, cube, ws);
    hipLaunchKernelGGL(scan_k, dim3(Bn), dim3(256), 0, stream, ws);
    hipLaunchKernelGGL(scatter_k, dim3(Bn * 1000), dim3(256), 0, stream, cube, dop, out, ws);
    hipLaunchKernelGGL(fill_k, dim3((Bn * Kn + 255) / 256), dim3(256), 0, stream, out, ws);
}